// Round 3
// baseline (979.982 us; speedup 1.0000x reference)
//
#include <hip/hip_runtime.h>

typedef float f32x4 __attribute__((ext_vector_type(4)));
typedef __bf16 bf16x8 __attribute__((ext_vector_type(8)));
typedef unsigned short ushort8v __attribute__((ext_vector_type(8)));

__device__ __forceinline__ unsigned short f2bf(float x) {
    unsigned u = __float_as_uint(x);
    u += 0x7fffu + ((u >> 16) & 1u);        // RNE
    return (unsigned short)(u >> 16);
}
__device__ __forceinline__ float bf2f(unsigned short s) {
    return __uint_as_float(((unsigned)s) << 16);
}

union V16 {
    int4 i;
    ushort8v u;
    bf16x8 b;
};

// ---------------- CSR build ----------------

__global__ void k_hist(const int* __restrict__ dst, int* __restrict__ cnt, int E) {
    int e = blockIdx.x * 256 + threadIdx.x;
    if (e < E) atomicAdd(&cnt[dst[e]], 1);
}

__global__ void k_dinv(const int* __restrict__ cnt, float* __restrict__ dinv, int N) {
    int i = blockIdx.x * 256 + threadIdx.x;
    if (i < N) dinv[i] = rsqrtf((float)(cnt[i] + 1));   // +1 self loop
}

__global__ void k_scan1(const int* __restrict__ cnt, int* __restrict__ incl,
                        int* __restrict__ bsums, int N) {
    __shared__ int s[1024];
    int t = threadIdx.x;
    int i = blockIdx.x * 1024 + t;
    int v = (i < N) ? cnt[i] : 0;
    s[t] = v;
    __syncthreads();
    for (int d = 1; d < 1024; d <<= 1) {
        int o = (t >= d) ? s[t - d] : 0;
        __syncthreads();
        s[t] += o;
        __syncthreads();
    }
    if (i < N) incl[i] = s[t];
    if (t == 1023) bsums[blockIdx.x] = s[1023];
}

__global__ void k_scan2(int* __restrict__ bsums, int NSB) {
    int t = threadIdx.x;          // 64 threads, one wave
    int v = (t < NSB) ? bsums[t] : 0;
    int x = v;
    for (int d = 1; d < 64; d <<= 1) {
        int o = __shfl_up(x, d, 64);
        if (t >= d) x += o;
    }
    if (t < NSB) bsums[t] = x - v;   // exclusive
}

__global__ void k_scan3(const int* __restrict__ cnt, const int* __restrict__ incl,
                        const int* __restrict__ bsums, int* __restrict__ offs,
                        int* __restrict__ cur, int N) {
    int i = blockIdx.x * 256 + threadIdx.x;
    if (i < N) {
        int o = incl[i] - cnt[i] + bsums[i >> 10];
        offs[i] = o;
        cur[i] = o;
    }
}

__global__ void k_fill(const int* __restrict__ src, const int* __restrict__ dst,
                       int* __restrict__ cur, int* __restrict__ csr, int E) {
    int e = blockIdx.x * 256 + threadIdx.x;
    if (e < E) {
        int d = dst[e];
        int p = atomicAdd(&cur[d], 1);
        csr[p] = src[e];
    }
}

// -------- weight transpose+convert: Bt[n][k] = bf16(W[k][n]), zero-padded K --------

__global__ void k_trans(const float* __restrict__ W, unsigned short* __restrict__ Bt,
                        int K, int KP) {
    int idx = blockIdx.x * 256 + threadIdx.x;
    if (idx >= 256 * KP) return;
    int n = idx / KP, k = idx - n * KP;
    float v = (k < K) ? W[(size_t)k * 256 + n] : 0.f;
    Bt[idx] = f2bf(v);
}

// ---------------- GEMM: out[m][n] = bf16( dinv[m] * sum_k A[m][k]*W[k][n] ) ----------------
// BM=64, BN=256, BK=32, 256 threads = 4 waves (2x2), 16x16x32 bf16 MFMA.
// LDS layout (shorts): A[64][32] at 0, B[256][32] at 2048; 16B chunk slot swizzled by ((row>>1)&3).

template <bool AF32>
__global__ __launch_bounds__(256, 2) void k_gemm(
    const float* __restrict__ Af, const unsigned short* __restrict__ Ab,
    const unsigned short* __restrict__ Bt, const float* __restrict__ dinv,
    unsigned short* __restrict__ out, int M, int K, int KP) {
    __shared__ __align__(16) unsigned short lds[20480];   // 2 x (2048 + 8192) shorts = 40KB
    const int tid = threadIdx.x;
    const int row0 = blockIdx.x * 64;
    const int w = tid >> 6, lane = tid & 63;
    const int wr = w >> 1, wc = w & 1;
    const int lm = lane & 15, kg = lane >> 4;
    const int KT = KP >> 5;

    f32x4 acc[2][8];
#pragma unroll
    for (int i = 0; i < 2; i++)
#pragma unroll
        for (int j = 0; j < 8; j++) acc[i][j] = f32x4{0.f, 0.f, 0.f, 0.f};

    const int sm = tid >> 2;       // A staging: row 0..63
    const int sc = tid & 3;        // A staging: 8-elem chunk 0..3
    int ar = row0 + sm;
    if (ar > M - 1) ar = M - 1;
    const int aoffs = sm * 32 + ((sc ^ ((sm >> 1) & 3)) * 8);
    const int bn = tid;            // B staging: one n-row per thread

    float av[8];
    int4 avb;
    int4 bv[4];

    // prologue: stage tile 0 into buffer 0
    {
        if (AF32) {
#pragma unroll
            for (int j = 0; j < 8; j++) {
                int kk = sc * 8 + j;
                av[j] = (kk < K) ? Af[(size_t)ar * K + kk] : 0.f;
            }
            V16 vv;
#pragma unroll
            for (int j = 0; j < 8; j++) vv.u[j] = f2bf(av[j]);
            *(ushort8v*)&lds[aoffs] = vv.u;
        } else {
            avb = *(const int4*)(Ab + (size_t)ar * K + sc * 8);
            *(int4*)&lds[aoffs] = avb;
        }
#pragma unroll
        for (int c = 0; c < 4; c++) {
            bv[c] = *(const int4*)(Bt + (size_t)bn * KP + c * 8);
            *(int4*)&lds[2048 + bn * 32 + ((c ^ ((bn >> 1) & 3)) * 8)] = bv[c];
        }
    }
    __syncthreads();

    for (int kt = 0; kt < KT; ++kt) {
        const int pb = (kt & 1) * 10240;
        const bool pre = (kt + 1 < KT);
        if (pre) {
            const int k0 = (kt + 1) << 5;
            if (AF32) {
#pragma unroll
                for (int j = 0; j < 8; j++) {
                    int kk = k0 + sc * 8 + j;
                    av[j] = (kk < K) ? Af[(size_t)ar * K + kk] : 0.f;
                }
            } else {
                avb = *(const int4*)(Ab + (size_t)ar * K + k0 + sc * 8);
            }
#pragma unroll
            for (int c = 0; c < 4; c++)
                bv[c] = *(const int4*)(Bt + (size_t)bn * KP + k0 + c * 8);
        }

        V16 afr[2], bfr[8];
#pragma unroll
        for (int mi = 0; mi < 2; mi++) {
            int r = wr * 32 + mi * 16 + lm;
            afr[mi].u = *(const ushort8v*)&lds[pb + r * 32 + ((kg ^ ((r >> 1) & 3)) * 8)];
        }
#pragma unroll
        for (int ni = 0; ni < 8; ni++) {
            int n = wc * 128 + ni * 16 + lm;
            bfr[ni].u = *(const ushort8v*)&lds[pb + 2048 + n * 32 + ((kg ^ ((n >> 1) & 3)) * 8)];
        }
#pragma unroll
        for (int mi = 0; mi < 2; mi++)
#pragma unroll
            for (int ni = 0; ni < 8; ni++)
                acc[mi][ni] = __builtin_amdgcn_mfma_f32_16x16x32_bf16(
                    afr[mi].b, bfr[ni].b, acc[mi][ni], 0, 0, 0);

        if (pre) {
            const int qb = ((kt & 1) ^ 1) * 10240;
            if (AF32) {
                V16 vv;
#pragma unroll
                for (int j = 0; j < 8; j++) vv.u[j] = f2bf(av[j]);
                *(ushort8v*)&lds[qb + aoffs] = vv.u;
            } else {
                *(int4*)&lds[qb + aoffs] = avb;
            }
#pragma unroll
            for (int c = 0; c < 4; c++)
                *(int4*)&lds[qb + 2048 + bn * 32 + ((c ^ ((bn >> 1) & 3)) * 8)] = bv[c];
        }
        __syncthreads();
    }

    // epilogue: D row = (lane>>4)*4 + reg, col = lane&15 (m89-verified layout)
#pragma unroll
    for (int mi = 0; mi < 2; mi++) {
#pragma unroll
        for (int q = 0; q < 4; q++) {
            int row = row0 + wr * 32 + mi * 16 + kg * 4 + q;
            if (row < M) {
                float dv = dinv[row];
#pragma unroll
                for (int ni = 0; ni < 8; ni++) {
                    int col = wc * 128 + ni * 16 + lm;
                    out[(size_t)row * 256 + col] = f2bf(acc[mi][ni][q] * dv);
                }
            }
        }
    }
}

// ---------------- aggregation (one wave per node, 4 cols per lane) ----------------

__device__ __forceinline__ void acc8(const unsigned short* p, float& a0, float& a1,
                                     float& a2, float& a3) {
    uint2 v = *(const uint2*)p;
    a0 += bf2f((unsigned short)(v.x & 0xffffu));
    a1 += bf2f((unsigned short)(v.x >> 16));
    a2 += bf2f((unsigned short)(v.y & 0xffffu));
    a3 += bf2f((unsigned short)(v.y >> 16));
}

__global__ __launch_bounds__(256) void k_agg1(
    const unsigned short* __restrict__ hs, const int* __restrict__ offs,
    const int* __restrict__ cnt, const int* __restrict__ csr,
    const float* __restrict__ dinv, const float* __restrict__ bias,
    unsigned short* __restrict__ out, int N) {
    int node = blockIdx.x * 4 + (threadIdx.x >> 6);
    if (node >= N) return;
    int lane = threadIdx.x & 63;
    int c0 = lane * 4;
    float a0 = 0, a1 = 0, a2 = 0, a3 = 0;
    acc8(hs + (size_t)node * 256 + c0, a0, a1, a2, a3);   // self loop
    int s = offs[node], e = s + cnt[node];
    for (int j = s; j < e; ++j) {
        int sr = csr[j];
        acc8(hs + (size_t)sr * 256 + c0, a0, a1, a2, a3);
    }
    float dv = dinv[node];
    float4 bb = *(const float4*)(bias + c0);
    float o0 = fmaxf(fmaf(a0, dv, bb.x), 0.f);
    float o1 = fmaxf(fmaf(a1, dv, bb.y), 0.f);
    float o2 = fmaxf(fmaf(a2, dv, bb.z), 0.f);
    float o3 = fmaxf(fmaf(a3, dv, bb.w), 0.f);
    uint2 ov;
    ov.x = (unsigned)f2bf(o0) | ((unsigned)f2bf(o1) << 16);
    ov.y = (unsigned)f2bf(o2) | ((unsigned)f2bf(o3) << 16);
    *(uint2*)(out + (size_t)node * 256 + c0) = ov;
}

__global__ __launch_bounds__(256) void k_aggsel(
    const unsigned short* __restrict__ hs, const int* __restrict__ offs,
    const int* __restrict__ cnt, const int* __restrict__ csr,
    const float* __restrict__ dinv, const float* __restrict__ bias,
    const int* __restrict__ vni, float* __restrict__ sel, int B) {
    int b = blockIdx.x * 4 + (threadIdx.x >> 6);
    if (b >= B) return;
    int node = vni[b];
    int lane = threadIdx.x & 63;
    int c0 = lane * 4;
    float a0 = 0, a1 = 0, a2 = 0, a3 = 0;
    acc8(hs + (size_t)node * 256 + c0, a0, a1, a2, a3);   // self loop
    int s = offs[node], e = s + cnt[node];
    for (int j = s; j < e; ++j) {
        int sr = csr[j];
        acc8(hs + (size_t)sr * 256 + c0, a0, a1, a2, a3);
    }
    float dv = dinv[node];
    float4 bb = *(const float4*)(bias + c0);
    float4 o;
    o.x = fmaxf(fmaf(a0, dv, bb.x), 0.f);
    o.y = fmaxf(fmaf(a1, dv, bb.y), 0.f);
    o.z = fmaxf(fmaf(a2, dv, bb.z), 0.f);
    o.w = fmaxf(fmaf(a3, dv, bb.w), 0.f);
    *(float4*)(sel + (size_t)b * 256 + c0) = o;
}

// ---------------- fused MLP head (fp32), 16 rows per 128-thread block ----------------

__global__ __launch_bounds__(128) void k_head(
    const float* __restrict__ sel, const float* __restrict__ wt,
    const float* __restrict__ mut, const float* __restrict__ Wh1,
    const float* __restrict__ bh1, const float* __restrict__ Wh2,
    const float* __restrict__ bh2, const float* __restrict__ Wh3,
    const float* __restrict__ bh3, float* __restrict__ out, int B) {
    __shared__ float Z[16][296];
    __shared__ float X1[16][128];
    __shared__ float X2[16][64];
    int t = threadIdx.x;
    int b0 = blockIdx.x * 16;
    for (int idx = t; idx < 16 * 296; idx += 128) {
        int r = idx / 296, c = idx - r * 296;
        int b = b0 + r;
        if (b > B - 1) b = B - 1;
        float v;
        if (c < 256) v = sel[(size_t)b * 256 + c];
        else if (c < 276) v = wt[b * 20 + (c - 256)];
        else v = mut[b * 20 + (c - 276)];
        Z[r][c] = v;
    }
    __syncthreads();
    {
        float acc[16];
        float bv = bh1[t];
#pragma unroll
        for (int r = 0; r < 16; r++) acc[r] = bv;
        for (int k = 0; k < 296; k++) {
            float wv = Wh1[k * 128 + t];
#pragma unroll
            for (int r = 0; r < 16; r++) acc[r] += Z[r][k] * wv;
        }
#pragma unroll
        for (int r = 0; r < 16; r++) X1[r][t] = fmaxf(acc[r], 0.f);
    }
    __syncthreads();
    if (t < 64) {
        float acc[16];
        float bv = bh2[t];
#pragma unroll
        for (int r = 0; r < 16; r++) acc[r] = bv;
        for (int k = 0; k < 128; k++) {
            float wv = Wh2[k * 64 + t];
#pragma unroll
            for (int r = 0; r < 16; r++) acc[r] += X1[r][k] * wv;
        }
#pragma unroll
        for (int r = 0; r < 16; r++) X2[r][t] = fmaxf(acc[r], 0.f);
    }
    __syncthreads();
    if (t < 16) {
        int b = b0 + t;
        if (b < B) {
            float s = bh3[0];
            for (int k = 0; k < 64; k++) s += X2[t][k] * Wh3[k];
            out[b] = s;
        }
    }
}

// ---------------- launcher ----------------

extern "C" void kernel_launch(void* const* d_in, const int* in_sizes, int n_in,
                              void* d_out, int out_size, void* d_ws, size_t ws_size,
                              hipStream_t stream) {
    const float* x   = (const float*)d_in[0];
    const float* wt  = (const float*)d_in[1];
    const float* mut = (const float*)d_in[2];
    const float* Wc1 = (const float*)d_in[3];
    const float* bc1 = (const float*)d_in[4];
    const float* Wc2 = (const float*)d_in[5];
    const float* bc2 = (const float*)d_in[6];
    const float* Wh1 = (const float*)d_in[7];
    const float* bh1 = (const float*)d_in[8];
    const float* Wh2 = (const float*)d_in[9];
    const float* bh2 = (const float*)d_in[10];
    const float* Wh3 = (const float*)d_in[11];
    const float* bh3 = (const float*)d_in[12];
    const int* ei    = (const int*)d_in[13];
    const int* vni   = (const int*)d_in[14];

    const int H   = in_sizes[4];             // 256
    const int DIN = in_sizes[3] / H;         // 1281
    const int N   = in_sizes[0] / DIN;       // 50000
    const int E   = in_sizes[13] / 2;        // 800000
    const int B   = in_sizes[14];            // 4096
    const int KP1 = ((DIN + 31) / 32) * 32;  // 1312

    char* wp = (char*)d_ws;
    size_t used = 0;
    auto alloc = [&](size_t bytes) -> void* {
        void* p = wp + used;
        used += (bytes + 255) & ~(size_t)255;
        return p;
    };
    int* cnt            = (int*)alloc((size_t)N * 4);
    int* incl           = (int*)alloc((size_t)N * 4);
    int* offs           = (int*)alloc((size_t)N * 4);
    int* cur            = (int*)alloc((size_t)N * 4);
    int* bsums          = (int*)alloc(64 * 4);
    float* dinv         = (float*)alloc((size_t)N * 4);
    int* csr            = (int*)alloc((size_t)E * 4);
    unsigned short* Bt1 = (unsigned short*)alloc((size_t)256 * KP1 * 2);
    unsigned short* Bt2 = (unsigned short*)alloc((size_t)256 * 256 * 2);
    unsigned short* hs1 = (unsigned short*)alloc((size_t)N * 256 * 2);
    unsigned short* h1  = (unsigned short*)alloc((size_t)N * 256 * 2);
    float* sel          = (float*)alloc((size_t)B * 256 * 4);
    unsigned short* hs2 = hs1;   // reuse: hs1 dead after k_agg1
    if (used > ws_size) return;  // visible failure instead of corruption

    hipMemsetAsync(cnt, 0, (size_t)N * 4, stream);
    k_hist<<<(E + 255) / 256, 256, 0, stream>>>(ei + E, cnt, E);
    k_dinv<<<(N + 255) / 256, 256, 0, stream>>>(cnt, dinv, N);
    const int NSB = (N + 1023) / 1024;
    k_scan1<<<NSB, 1024, 0, stream>>>(cnt, incl, bsums, N);
    k_scan2<<<1, 64, 0, stream>>>(bsums, NSB);
    k_scan3<<<(N + 255) / 256, 256, 0, stream>>>(cnt, incl, bsums, offs, cur, N);
    k_fill<<<(E + 255) / 256, 256, 0, stream>>>(ei, ei + E, cur, csr, E);
    k_trans<<<(256 * KP1 + 255) / 256, 256, 0, stream>>>(Wc1, Bt1, DIN, KP1);
    k_trans<<<(256 * 256 + 255) / 256, 256, 0, stream>>>(Wc2, Bt2, 256, 256);

    k_gemm<true><<<(N + 63) / 64, 256, 0, stream>>>(x, nullptr, Bt1, dinv, hs1, N, DIN, KP1);
    k_agg1<<<(N + 3) / 4, 256, 0, stream>>>(hs1, offs, cnt, csr, dinv, bc1, h1, N);
    k_gemm<false><<<(N + 63) / 64, 256, 0, stream>>>(nullptr, h1, Bt2, dinv, hs2, N, 256, 256);
    k_aggsel<<<(B + 3) / 4, 256, 0, stream>>>(hs2, offs, cnt, csr, dinv, bc2, vni, sel, B);
    k_head<<<(B + 15) / 16, 128, 0, stream>>>(sel, wt, mut, Wh1, bh1, Wh2, bh2, Wh3, bh3,
                                              (float*)d_out, B);
}

// Round 4
// 719.700 us; speedup vs baseline: 1.3617x; 1.3617x over previous
//
#include <hip/hip_runtime.h>

typedef float f32x4 __attribute__((ext_vector_type(4)));
typedef __bf16 bf16x8 __attribute__((ext_vector_type(8)));
typedef unsigned short ushort8v __attribute__((ext_vector_type(8)));

__device__ __forceinline__ unsigned short f2bf(float x) {
    unsigned u = __float_as_uint(x);
    u += 0x7fffu + ((u >> 16) & 1u);        // RNE
    return (unsigned short)(u >> 16);
}
__device__ __forceinline__ float bf2f(unsigned short s) {
    return __uint_as_float(((unsigned)s) << 16);
}

union V16 {
    int4 i;
    ushort8v u;
    bf16x8 b;
};

// async global->LDS, 16B per lane; LDS dest must be wave-uniform base (lane*16 auto).
__device__ __forceinline__ void gl16(const void* g, void* l) {
    __builtin_amdgcn_global_load_lds(
        (const __attribute__((address_space(1))) unsigned int*)g,
        (__attribute__((address_space(3))) unsigned int*)l, 16, 0, 0);
}

// ---------------- CSR build ----------------

__global__ void k_hist(const int* __restrict__ dst, int* __restrict__ cnt, int E) {
    int e = blockIdx.x * 256 + threadIdx.x;
    if (e < E) atomicAdd(&cnt[dst[e]], 1);
}

__global__ void k_dinv(const int* __restrict__ cnt, float* __restrict__ dinv, int N) {
    int i = blockIdx.x * 256 + threadIdx.x;
    if (i < N) dinv[i] = rsqrtf((float)(cnt[i] + 1));   // +1 self loop
}

__global__ void k_scan1(const int* __restrict__ cnt, int* __restrict__ incl,
                        int* __restrict__ bsums, int N) {
    __shared__ int s[1024];
    int t = threadIdx.x;
    int i = blockIdx.x * 1024 + t;
    int v = (i < N) ? cnt[i] : 0;
    s[t] = v;
    __syncthreads();
    for (int d = 1; d < 1024; d <<= 1) {
        int o = (t >= d) ? s[t - d] : 0;
        __syncthreads();
        s[t] += o;
        __syncthreads();
    }
    if (i < N) incl[i] = s[t];
    if (t == 1023) bsums[blockIdx.x] = s[1023];
}

__global__ void k_scan2(int* __restrict__ bsums, int NSB) {
    int t = threadIdx.x;          // 64 threads, one wave
    int v = (t < NSB) ? bsums[t] : 0;
    int x = v;
    for (int d = 1; d < 64; d <<= 1) {
        int o = __shfl_up(x, d, 64);
        if (t >= d) x += o;
    }
    if (t < NSB) bsums[t] = x - v;   // exclusive
}

__global__ void k_scan3(const int* __restrict__ cnt, const int* __restrict__ incl,
                        const int* __restrict__ bsums, int* __restrict__ offs,
                        int* __restrict__ cur, int N) {
    int i = blockIdx.x * 256 + threadIdx.x;
    if (i < N) {
        int o = incl[i] - cnt[i] + bsums[i >> 10];
        offs[i] = o;
        cur[i] = o;
    }
}

__global__ void k_fill(const int* __restrict__ src, const int* __restrict__ dst,
                       int* __restrict__ cur, int* __restrict__ csr, int E) {
    int e = blockIdx.x * 256 + threadIdx.x;
    if (e < E) {
        int d = dst[e];
        int p = atomicAdd(&cur[d], 1);
        csr[p] = src[e];
    }
}

// -------- weight transpose+convert: Bt[n][k] = bf16(W[k][n]), zero-padded K --------

__global__ void k_trans(const float* __restrict__ W, unsigned short* __restrict__ Bt,
                        int K, int KP) {
    int idx = blockIdx.x * 256 + threadIdx.x;
    if (idx >= 256 * KP) return;
    int n = idx / KP, k = idx - n * KP;
    float v = (k < K) ? W[(size_t)k * 256 + n] : 0.f;
    Bt[idx] = f2bf(v);
}

// ---------------- GEMM: out[m][n] = bf16( dinv[m] * sum_k A[m][k]*W[k][n] ) ----------------
// BM=64, BN=256, BK=32, 256 threads = 4 waves (2x2), 16x16x32 bf16 MFMA.
// Staging via global_load_lds(16B) with pre-swizzled GLOBAL source (linear LDS dest):
//   AF32: A tile fp32 [64][32] f32, 8 slots/row, slot s of row r holds chunk s^(r&7);
//         frag read = 2x ds_read_b128 + cvt to bf16 (balanced: 8 lanes per bank-quad, 0 conflict).
//   bf16: A tile [64][32] bf16, 4 slots/row, slot s holds chunk s^((r>>1)&3)  (measured 0 conflict).
//   B tile [256][32] bf16, same 4-slot swizzle.
// One barrier per K-step (m97 structure): stage(next) -> ds_read(cur) -> MFMA -> syncthreads.

template <bool AF32>
__global__ __launch_bounds__(256, 3) void k_gemm(
    const float* __restrict__ Af, const unsigned short* __restrict__ Ab,
    const unsigned short* __restrict__ Bt, const float* __restrict__ dinv,
    unsigned short* __restrict__ out, int M, int K, int KP) {
    constexpr int ASH = AF32 ? 4096 : 2048;      // A tile size in shorts (8KB f32 / 4KB bf16)
    constexpr int BUF = ASH + 8192;              // + B tile 16KB
    __shared__ __align__(16) unsigned short lds[2 * BUF];
    const int tid = threadIdx.x;
    const int w = tid >> 6, lane = tid & 63;
    const int wr = w >> 1, wc = w & 1;
    const int lm = lane & 15, kg = lane >> 4;
    const int row0 = blockIdx.x * 64;
    const int KT = KP >> 5;

    f32x4 acc[2][8];
#pragma unroll
    for (int i = 0; i < 2; i++)
#pragma unroll
        for (int j = 0; j < 8; j++) acc[i][j] = f32x4{0.f, 0.f, 0.f, 0.f};

    // ---- staging lane decomposition (constant per thread) ----
    const int a8r = lane >> 3, a8c = lane & 7;   // fp32 A: 8 rows x 8 slots per instr
    const int a4r = lane >> 2, a4c = lane & 3;   // bf16 A/B: 16 rows x 4 slots per instr

    auto stage = [&](int b, int kt) {
        const int k0 = kt << 5;
        if (AF32) {
            if (kt == KT - 1) {
                // register path for the K-tail tile: guarded loads, zero-fill k>=K
#pragma unroll
                for (int cc = 0; cc < 2; cc++) {
                    int id = tid * 2 + cc;            // 0..511 chunk id
                    int r = id >> 3, s = id & 7;
                    int gr = row0 + r; if (gr > M - 1) gr = M - 1;
                    int g = s ^ (r & 7);
                    f32x4 v;
#pragma unroll
                    for (int j = 0; j < 4; j++) {
                        int kk = k0 + g * 4 + j;
                        v[j] = (kk < K) ? Af[(size_t)gr * K + kk] : 0.f;
                    }
                    *(f32x4*)&lds[b * BUF + r * 64 + s * 8] = v;
                }
            } else {
#pragma unroll
                for (int j = 0; j < 2; j++) {
                    int r = w * 16 + j * 8 + a8r;
                    int gr = row0 + r; if (gr > M - 1) gr = M - 1;
                    int g = a8c ^ (r & 7);
                    gl16(Af + (size_t)gr * K + k0 + g * 4,
                         &lds[b * BUF + (w * 16 + j * 8) * 64]);
                }
            }
        } else {
            int r = w * 16 + a4r;
            int gr = row0 + r; if (gr > M - 1) gr = M - 1;
            int g = a4c ^ ((r >> 1) & 3);
            gl16(Ab + (size_t)gr * KP + k0 + g * 8, &lds[b * BUF + (w * 16) * 32]);
        }
#pragma unroll
        for (int j = 0; j < 4; j++) {
            int n = w * 64 + j * 16 + a4r;
            int g = a4c ^ ((n >> 1) & 3);
            gl16(Bt + (size_t)n * KP + k0 + g * 8,
                 &lds[b * BUF + ASH + (w * 64 + j * 16) * 32]);
        }
    };

    stage(0, 0);
    __syncthreads();

    for (int kt = 0; kt < KT; ++kt) {
        if (kt + 1 < KT) stage((kt + 1) & 1, kt + 1);

        const int pb = (kt & 1) * BUF;
        V16 afr[2], bfr[8];
        if (AF32) {
#pragma unroll
            for (int mi = 0; mi < 2; mi++) {
                int r = wr * 32 + mi * 16 + lm;
                int s0 = (2 * kg) ^ (r & 7), s1 = (2 * kg + 1) ^ (r & 7);
                f32x4 lo = *(const f32x4*)&lds[pb + r * 64 + s0 * 8];
                f32x4 hi = *(const f32x4*)&lds[pb + r * 64 + s1 * 8];
#pragma unroll
                for (int j = 0; j < 4; j++) {
                    afr[mi].b[j] = (__bf16)lo[j];
                    afr[mi].b[4 + j] = (__bf16)hi[j];
                }
            }
        } else {
#pragma unroll
            for (int mi = 0; mi < 2; mi++) {
                int r = wr * 32 + mi * 16 + lm;
                afr[mi].u = *(const ushort8v*)&lds[pb + r * 32 + ((kg ^ ((r >> 1) & 3)) * 8)];
            }
        }
#pragma unroll
        for (int ni = 0; ni < 8; ni++) {
            int n = wc * 128 + ni * 16 + lm;
            bfr[ni].u = *(const ushort8v*)&lds[pb + ASH + n * 32 + ((kg ^ ((n >> 1) & 3)) * 8)];
        }
#pragma unroll
        for (int mi = 0; mi < 2; mi++)
#pragma unroll
            for (int ni = 0; ni < 8; ni++)
                acc[mi][ni] = __builtin_amdgcn_mfma_f32_16x16x32_bf16(
                    afr[mi].b, bfr[ni].b, acc[mi][ni], 0, 0, 0);

        __syncthreads();
    }

    // epilogue: D row = (lane>>4)*4 + reg, col = lane&15 (m89-verified layout)
#pragma unroll
    for (int mi = 0; mi < 2; mi++) {
#pragma unroll
        for (int q = 0; q < 4; q++) {
            int row = row0 + wr * 32 + mi * 16 + kg * 4 + q;
            if (row < M) {
                float dv = dinv[row];
#pragma unroll
                for (int ni = 0; ni < 8; ni++) {
                    int col = wc * 128 + ni * 16 + lm;
                    out[(size_t)row * 256 + col] = f2bf(acc[mi][ni][q] * dv);
                }
            }
        }
    }
}

// ---------------- aggregation (one wave per node, 4 cols per lane) ----------------

__device__ __forceinline__ void acc8(const unsigned short* p, float& a0, float& a1,
                                     float& a2, float& a3) {
    uint2 v = *(const uint2*)p;
    a0 += bf2f((unsigned short)(v.x & 0xffffu));
    a1 += bf2f((unsigned short)(v.x >> 16));
    a2 += bf2f((unsigned short)(v.y & 0xffffu));
    a3 += bf2f((unsigned short)(v.y >> 16));
}

__global__ __launch_bounds__(256) void k_agg1(
    const unsigned short* __restrict__ hs, const int* __restrict__ offs,
    const int* __restrict__ cnt, const int* __restrict__ csr,
    const float* __restrict__ dinv, const float* __restrict__ bias,
    unsigned short* __restrict__ out, int N) {
    int node = blockIdx.x * 4 + (threadIdx.x >> 6);
    if (node >= N) return;
    int lane = threadIdx.x & 63;
    int c0 = lane * 4;
    float a0 = 0, a1 = 0, a2 = 0, a3 = 0;
    acc8(hs + (size_t)node * 256 + c0, a0, a1, a2, a3);   // self loop
    int s = offs[node], e = s + cnt[node];
    for (int j = s; j < e; ++j) {
        int sr = csr[j];
        acc8(hs + (size_t)sr * 256 + c0, a0, a1, a2, a3);
    }
    float dv = dinv[node];
    float4 bb = *(const float4*)(bias + c0);
    float o0 = fmaxf(fmaf(a0, dv, bb.x), 0.f);
    float o1 = fmaxf(fmaf(a1, dv, bb.y), 0.f);
    float o2 = fmaxf(fmaf(a2, dv, bb.z), 0.f);
    float o3 = fmaxf(fmaf(a3, dv, bb.w), 0.f);
    uint2 ov;
    ov.x = (unsigned)f2bf(o0) | ((unsigned)f2bf(o1) << 16);
    ov.y = (unsigned)f2bf(o2) | ((unsigned)f2bf(o3) << 16);
    *(uint2*)(out + (size_t)node * 256 + c0) = ov;
}

__global__ __launch_bounds__(256) void k_aggsel(
    const unsigned short* __restrict__ hs, const int* __restrict__ offs,
    const int* __restrict__ cnt, const int* __restrict__ csr,
    const float* __restrict__ dinv, const float* __restrict__ bias,
    const int* __restrict__ vni, float* __restrict__ sel, int B) {
    int b = blockIdx.x * 4 + (threadIdx.x >> 6);
    if (b >= B) return;
    int node = vni[b];
    int lane = threadIdx.x & 63;
    int c0 = lane * 4;
    float a0 = 0, a1 = 0, a2 = 0, a3 = 0;
    acc8(hs + (size_t)node * 256 + c0, a0, a1, a2, a3);   // self loop
    int s = offs[node], e = s + cnt[node];
    for (int j = s; j < e; ++j) {
        int sr = csr[j];
        acc8(hs + (size_t)sr * 256 + c0, a0, a1, a2, a3);
    }
    float dv = dinv[node];
    float4 bb = *(const float4*)(bias + c0);
    float4 o;
    o.x = fmaxf(fmaf(a0, dv, bb.x), 0.f);
    o.y = fmaxf(fmaf(a1, dv, bb.y), 0.f);
    o.z = fmaxf(fmaf(a2, dv, bb.z), 0.f);
    o.w = fmaxf(fmaf(a3, dv, bb.w), 0.f);
    *(float4*)(sel + (size_t)b * 256 + c0) = o;
}

// ---------------- fused MLP head (fp32), 16 rows per 128-thread block ----------------

__global__ __launch_bounds__(128) void k_head(
    const float* __restrict__ sel, const float* __restrict__ wt,
    const float* __restrict__ mut, const float* __restrict__ Wh1,
    const float* __restrict__ bh1, const float* __restrict__ Wh2,
    const float* __restrict__ bh2, const float* __restrict__ Wh3,
    const float* __restrict__ bh3, float* __restrict__ out, int B) {
    __shared__ float Z[16][296];
    __shared__ float X1[16][128];
    __shared__ float X2[16][64];
    int t = threadIdx.x;
    int b0 = blockIdx.x * 16;
    for (int idx = t; idx < 16 * 296; idx += 128) {
        int r = idx / 296, c = idx - r * 296;
        int b = b0 + r;
        if (b > B - 1) b = B - 1;
        float v;
        if (c < 256) v = sel[(size_t)b * 256 + c];
        else if (c < 276) v = wt[b * 20 + (c - 256)];
        else v = mut[b * 20 + (c - 276)];
        Z[r][c] = v;
    }
    __syncthreads();
    {
        float acc[16];
        float bv = bh1[t];
#pragma unroll
        for (int r = 0; r < 16; r++) acc[r] = bv;
        for (int k = 0; k < 296; k++) {
            float wv = Wh1[k * 128 + t];
#pragma unroll
            for (int r = 0; r < 16; r++) acc[r] += Z[r][k] * wv;
        }
#pragma unroll
        for (int r = 0; r < 16; r++) X1[r][t] = fmaxf(acc[r], 0.f);
    }
    __syncthreads();
    if (t < 64) {
        float acc[16];
        float bv = bh2[t];
#pragma unroll
        for (int r = 0; r < 16; r++) acc[r] = bv;
        for (int k = 0; k < 128; k++) {
            float wv = Wh2[k * 64 + t];
#pragma unroll
            for (int r = 0; r < 16; r++) acc[r] += X1[r][k] * wv;
        }
#pragma unroll
        for (int r = 0; r < 16; r++) X2[r][t] = fmaxf(acc[r], 0.f);
    }
    __syncthreads();
    if (t < 16) {
        int b = b0 + t;
        if (b < B) {
            float s = bh3[0];
            for (int k = 0; k < 64; k++) s += X2[t][k] * Wh3[k];
            out[b] = s;
        }
    }
}

// ---------------- launcher ----------------

extern "C" void kernel_launch(void* const* d_in, const int* in_sizes, int n_in,
                              void* d_out, int out_size, void* d_ws, size_t ws_size,
                              hipStream_t stream) {
    const float* x   = (const float*)d_in[0];
    const float* wt  = (const float*)d_in[1];
    const float* mut = (const float*)d_in[2];
    const float* Wc1 = (const float*)d_in[3];
    const float* bc1 = (const float*)d_in[4];
    const float* Wc2 = (const float*)d_in[5];
    const float* bc2 = (const float*)d_in[6];
    const float* Wh1 = (const float*)d_in[7];
    const float* bh1 = (const float*)d_in[8];
    const float* Wh2 = (const float*)d_in[9];
    const float* bh2 = (const float*)d_in[10];
    const float* Wh3 = (const float*)d_in[11];
    const float* bh3 = (const float*)d_in[12];
    const int* ei    = (const int*)d_in[13];
    const int* vni   = (const int*)d_in[14];

    const int H   = in_sizes[4];             // 256
    const int DIN = in_sizes[3] / H;         // 1281
    const int N   = in_sizes[0] / DIN;       // 50000
    const int E   = in_sizes[13] / 2;        // 800000
    const int B   = in_sizes[14];            // 4096
    const int KP1 = ((DIN + 31) / 32) * 32;  // 1312

    char* wp = (char*)d_ws;
    size_t used = 0;
    auto alloc = [&](size_t bytes) -> void* {
        void* p = wp + used;
        used += (bytes + 255) & ~(size_t)255;
        return p;
    };
    int* cnt            = (int*)alloc((size_t)N * 4);
    int* incl           = (int*)alloc((size_t)N * 4);
    int* offs           = (int*)alloc((size_t)N * 4);
    int* cur            = (int*)alloc((size_t)N * 4);
    int* bsums          = (int*)alloc(64 * 4);
    float* dinv         = (float*)alloc((size_t)N * 4);
    int* csr            = (int*)alloc((size_t)E * 4);
    unsigned short* Bt1 = (unsigned short*)alloc((size_t)256 * KP1 * 2);
    unsigned short* Bt2 = (unsigned short*)alloc((size_t)256 * 256 * 2);
    unsigned short* hs1 = (unsigned short*)alloc((size_t)N * 256 * 2);
    unsigned short* h1  = (unsigned short*)alloc((size_t)N * 256 * 2);
    float* sel          = (float*)alloc((size_t)B * 256 * 4);
    unsigned short* hs2 = hs1;   // reuse: hs1 dead after k_agg1
    if (used > ws_size) return;  // visible failure instead of corruption

    hipMemsetAsync(cnt, 0, (size_t)N * 4, stream);
    k_hist<<<(E + 255) / 256, 256, 0, stream>>>(ei + E, cnt, E);
    k_dinv<<<(N + 255) / 256, 256, 0, stream>>>(cnt, dinv, N);
    const int NSB = (N + 1023) / 1024;
    k_scan1<<<NSB, 1024, 0, stream>>>(cnt, incl, bsums, N);
    k_scan2<<<1, 64, 0, stream>>>(bsums, NSB);
    k_scan3<<<(N + 255) / 256, 256, 0, stream>>>(cnt, incl, bsums, offs, cur, N);
    k_fill<<<(E + 255) / 256, 256, 0, stream>>>(ei, ei + E, cur, csr, E);
    k_trans<<<(256 * KP1 + 255) / 256, 256, 0, stream>>>(Wc1, Bt1, DIN, KP1);
    k_trans<<<(256 * 256 + 255) / 256, 256, 0, stream>>>(Wc2, Bt2, 256, 256);

    k_gemm<true><<<(N + 63) / 64, 256, 0, stream>>>(x, nullptr, Bt1, dinv, hs1, N, DIN, KP1);
    k_agg1<<<(N + 3) / 4, 256, 0, stream>>>(hs1, offs, cnt, csr, dinv, bc1, h1, N);
    k_gemm<false><<<(N + 63) / 64, 256, 0, stream>>>(nullptr, h1, Bt2, dinv, hs2, N, 256, 256);
    k_aggsel<<<(B + 3) / 4, 256, 0, stream>>>(hs2, offs, cnt, csr, dinv, bc2, vni, sel, B);
    k_head<<<(B + 15) / 16, 128, 0, stream>>>(sel, wt, mut, Wh1, bh1, Wh2, bh2, Wh3, bh3,
                                              (float*)d_out, B);
}